// Round 12
// baseline (2674.511 us; speedup 1.0000x reference)
//
#include <hip/hip_runtime.h>

typedef unsigned short u16;
typedef __attribute__((ext_vector_type(8))) short bf16x8;
typedef __attribute__((ext_vector_type(4))) float f32x4;

#define N_TOK 32768
#define DIM   1280
#define NH    4
#define DH    320
#define FFD   256
#define NLAYER 2
#define NB    64
#define TD    3840  // 3*DIM
#define KVD   2560  // 2*DIM

#define GLD16(gp, lp) __builtin_amdgcn_global_load_lds( \
    (const __attribute__((address_space(1))) unsigned int*)(const void*)(gp), \
    (__attribute__((address_space(3))) unsigned int*)(void*)(lp), 16, 0, 0)

__device__ __forceinline__ float b2f(u16 v) {
    union { unsigned u; float f; } c; c.u = ((unsigned)v) << 16; return c.f;
}
__device__ __forceinline__ u16 f2b(float f) {
    union { float f; unsigned u; } c; c.f = f;
    unsigned r = c.u + 0x7fffu + ((c.u >> 16) & 1u);
    return (u16)(r >> 16);
}

// ---------------- f32 -> bf16 bulk convert -------------------------------------
__global__ __launch_bounds__(256) void k_f32_to_bf16(
    const float* __restrict__ in, u16* __restrict__ out, long n)
{
    long i = ((long)blockIdx.x * 256 + threadIdx.x) * 4;
    if (i >= n) return;
    float4 v = *(const float4*)&in[i];
    ushort4 o; o.x = f2b(v.x); o.y = f2b(v.y); o.z = f2b(v.z); o.w = f2b(v.w);
    *(ushort4*)&out[i] = o;
}

// ---------------- merged weight convert (6 segments, one launch) ---------------
#define E0 9830400L   // Wqkv  2*3840*1280
#define E1 13107200L  // +Wo   2*1280*1280
#define E2 13762560L  // +W1   2*256*1280
#define E3 14417920L  // +W2   2*1280*256
#define E4 14745600L  // +Wm1  256*1280
#define E5 15073280L  // +Wm2  1280*256
__global__ __launch_bounds__(256) void k_conv_weights(
    const float* __restrict__ Wqkv, const float* __restrict__ Wo,
    const float* __restrict__ W1,   const float* __restrict__ W2,
    const float* __restrict__ Wm1,  const float* __restrict__ Wm2,
    u16* __restrict__ d0, u16* __restrict__ d1, u16* __restrict__ d2,
    u16* __restrict__ d3, u16* __restrict__ d4, u16* __restrict__ d5)
{
    long i = ((long)blockIdx.x * 256 + threadIdx.x) * 4;
    if (i >= E5) return;
    const float* src; u16* dst; long off;
    if      (i < E0) { src = Wqkv; dst = d0; off = i; }
    else if (i < E1) { src = Wo;   dst = d1; off = i - E0; }
    else if (i < E2) { src = W1;   dst = d2; off = i - E1; }
    else if (i < E3) { src = W2;   dst = d3; off = i - E2; }
    else if (i < E4) { src = Wm1;  dst = d4; off = i - E3; }
    else             { src = Wm2;  dst = d5; off = i - E4; }
    float4 v = *(const float4*)&src[off];
    ushort4 o; o.x = f2b(v.x); o.y = f2b(v.y); o.z = f2b(v.z); o.w = f2b(v.w);
    *(ushort4*)&dst[off] = o;
}

// ---------------- per-graph offsets via binary search on sorted batch ----------
__global__ void k_offsets(const int* __restrict__ batch, int* __restrict__ offs) {
    int b = threadIdx.x;
    if (b > NB) return;
    int lo = 0, hi = N_TOK;
    while (lo < hi) {
        int mid = (lo + hi) >> 1;
        if (batch[mid] < b) lo = mid + 1; else hi = mid;
    }
    offs[b] = lo;   // offs[64] == N_TOK
}

// ------ MFMA GEMM: C[M,N] = A_bf16[M,K](lda) @ W_bf16[N,K]^T + bias_f32
__global__ __launch_bounds__(256) void k_gemm_mfma(
    const u16* __restrict__ A, int lda,
    const u16* __restrict__ W,
    const float* __restrict__ bias,
    void* __restrict__ Cv, int ldc,
    int K, int relu, int store_f32)
{
    __shared__ u16 Asm[128 * 64];
    __shared__ u16 Bsm[128 * 64];
    const int t    = threadIdx.x;
    const int lane = t & 63;
    const int w    = t >> 6;
    const int wr   = w >> 1, wc = w & 1;
    const long mBase = (long)blockIdx.y * 128;
    const long nBase = (long)blockIdx.x * 128;
    const int srow = lane >> 3;
    const int scol = (lane & 7) * 8;

    f32x4 acc[4][4];
    #pragma unroll
    for (int m = 0; m < 4; ++m)
        #pragma unroll
        for (int n = 0; n < 4; ++n) acc[m][n] = (f32x4){0.f, 0.f, 0.f, 0.f};

    for (int k0 = 0; k0 < K; k0 += 64) {
        __syncthreads();
        #pragma unroll
        for (int i = 0; i < 4; ++i) {
            const int c = w * 4 + i;
            const u16* ga = &A[(mBase + c * 8 + srow) * (long)lda + k0 + scol];
            const u16* gb = &W[(nBase + c * 8 + srow) * (long)K   + k0 + scol];
            GLD16(ga, &Asm[c * 512]);
            GLD16(gb, &Bsm[c * 512]);
        }
        __syncthreads();
        #pragma unroll
        for (int kk = 0; kk < 2; ++kk) {
            const int kc = kk * 32 + (lane >> 4) * 8;
            bf16x8 af[4], bfr[4];
            #pragma unroll
            for (int m = 0; m < 4; ++m)
                af[m] = *(const bf16x8*)&Asm[(wr * 64 + m * 16 + (lane & 15)) * 64 + kc];
            #pragma unroll
            for (int n = 0; n < 4; ++n)
                bfr[n] = *(const bf16x8*)&Bsm[(wc * 64 + n * 16 + (lane & 15)) * 64 + kc];
            #pragma unroll
            for (int m = 0; m < 4; ++m)
                #pragma unroll
                for (int n = 0; n < 4; ++n)
                    acc[m][n] = __builtin_amdgcn_mfma_f32_16x16x32_bf16(
                        af[m], bfr[n], acc[m][n], 0, 0, 0);
        }
    }

    const int ccol  = lane & 15;
    const int crow0 = (lane >> 4) * 4;
    #pragma unroll
    for (int m = 0; m < 4; ++m) {
        #pragma unroll
        for (int n = 0; n < 4; ++n) {
            const long col = nBase + wc * 64 + n * 16 + ccol;
            const float bv = bias[col];
            #pragma unroll
            for (int r = 0; r < 4; ++r) {
                const long row = mBase + wr * 64 + m * 16 + crow0 + r;
                float v = acc[m][n][r] + bv;
                if (relu) v = fmaxf(v, 0.f);
                if (store_f32) ((float*)Cv)[row * (long)ldc + col] = v;
                else           ((u16*)Cv)[row * (long)ldc + col] = f2b(v);
            }
        }
    }
}

// ------ fused QKV GEMM: N=3840; cols [0,1280) -> qd (ldc=DIM), rest -> kvd -----
__global__ __launch_bounds__(256) void k_gemm_qkv(
    const u16* __restrict__ A,
    const u16* __restrict__ W,
    const float* __restrict__ bias,
    u16* __restrict__ qd, u16* __restrict__ kvd)
{
    __shared__ u16 Asm[128 * 64];
    __shared__ u16 Bsm[128 * 64];
    const int t    = threadIdx.x;
    const int lane = t & 63;
    const int w    = t >> 6;
    const int wr   = w >> 1, wc = w & 1;
    const long mBase = (long)blockIdx.y * 128;
    const long nBase = (long)blockIdx.x * 128;
    const int srow = lane >> 3;
    const int scol = (lane & 7) * 8;

    f32x4 acc[4][4];
    #pragma unroll
    for (int m = 0; m < 4; ++m)
        #pragma unroll
        for (int n = 0; n < 4; ++n) acc[m][n] = (f32x4){0.f, 0.f, 0.f, 0.f};

    for (int k0 = 0; k0 < DIM; k0 += 64) {
        __syncthreads();
        #pragma unroll
        for (int i = 0; i < 4; ++i) {
            const int c = w * 4 + i;
            const u16* ga = &A[(mBase + c * 8 + srow) * (long)DIM + k0 + scol];
            const u16* gb = &W[(nBase + c * 8 + srow) * (long)DIM + k0 + scol];
            GLD16(ga, &Asm[c * 512]);
            GLD16(gb, &Bsm[c * 512]);
        }
        __syncthreads();
        #pragma unroll
        for (int kk = 0; kk < 2; ++kk) {
            const int kc = kk * 32 + (lane >> 4) * 8;
            bf16x8 af[4], bfr[4];
            #pragma unroll
            for (int m = 0; m < 4; ++m)
                af[m] = *(const bf16x8*)&Asm[(wr * 64 + m * 16 + (lane & 15)) * 64 + kc];
            #pragma unroll
            for (int n = 0; n < 4; ++n)
                bfr[n] = *(const bf16x8*)&Bsm[(wc * 64 + n * 16 + (lane & 15)) * 64 + kc];
            #pragma unroll
            for (int m = 0; m < 4; ++m)
                #pragma unroll
                for (int n = 0; n < 4; ++n)
                    acc[m][n] = __builtin_amdgcn_mfma_f32_16x16x32_bf16(
                        af[m], bfr[n], acc[m][n], 0, 0, 0);
        }
    }

    const int ccol  = lane & 15;
    const int crow0 = (lane >> 4) * 4;
    const bool isQ = (nBase < DIM);           // uniform per block (128 | 1280)
    #pragma unroll
    for (int m = 0; m < 4; ++m) {
        #pragma unroll
        for (int n = 0; n < 4; ++n) {
            const long col = nBase + wc * 64 + n * 16 + ccol;
            const float bv = bias[col];
            #pragma unroll
            for (int r = 0; r < 4; ++r) {
                const long row = mBase + wr * 64 + m * 16 + crow0 + r;
                float v = acc[m][n][r] + bv;
                if (isQ) qd[row * (long)DIM + col]          = f2b(v);
                else     kvd[row * (long)KVD + (col - DIM)] = f2b(v);
            }
        }
    }
}

// --------- fused residual + LayerNorm, wave-per-row, fully vectorized ----------
// block = 256 thr = 4 waves = 4 rows; lane owns 20 contiguous elems (5 x uint2).
// No LDS, no barriers: 64-lane shfl_xor butterfly for mean/var.
__global__ __launch_bounds__(256) void k_ln_residual(
    const u16* __restrict__ a, const u16* __restrict__ delta,
    const float* __restrict__ w, const float* __restrict__ bb,
    u16* __restrict__ out)
{
    const int lane = threadIdx.x & 63;
    const long row = (long)blockIdx.x * 4 + (threadIdx.x >> 6);
    const long base = row * DIM + lane * 20;
    float v[20];
    float s = 0.f, s2 = 0.f;
    #pragma unroll
    for (int k = 0; k < 5; ++k) {
        uint2 ua = *(const uint2*)&a[base + k * 4];
        uint2 ud = *(const uint2*)&delta[base + k * 4];
        u16 ah[4], dh[4];
        *(uint2*)ah = ua; *(uint2*)dh = ud;
        #pragma unroll
        for (int e = 0; e < 4; ++e) {
            float xv = b2f(ah[e]) + b2f(dh[e]);
            v[k * 4 + e] = xv; s += xv; s2 += xv * xv;
        }
    }
    #pragma unroll
    for (int off = 32; off > 0; off >>= 1) {
        s  += __shfl_xor(s, off);
        s2 += __shfl_xor(s2, off);
    }
    const float mu  = s * (1.f / DIM);
    const float var = s2 * (1.f / DIM) - mu * mu;
    const float inv = rsqrtf(fmaxf(var, 0.f) + 1e-5f);
    const int cb = lane * 20;
    #pragma unroll
    for (int k = 0; k < 5; ++k) {
        float4 wv = *(const float4*)&w[cb + k * 4];
        float4 bv = *(const float4*)&bb[cb + k * 4];
        u16 oh[4];
        oh[0] = f2b((v[k * 4 + 0] - mu) * inv * wv.x + bv.x);
        oh[1] = f2b((v[k * 4 + 1] - mu) * inv * wv.y + bv.y);
        oh[2] = f2b((v[k * 4 + 2] - mu) * inv * wv.z + bv.z);
        oh[3] = f2b((v[k * 4 + 3] - mu) * inv * wv.w + bv.w);
        *(uint2*)&out[base + k * 4] = *(uint2*)oh;
    }
}

// -------- MFMA flash attention (r9 structure, best measured): QBLK=32, 4 waves,
// K staged to LDS (union with V^T), V loads in softmax phase, XCD swizzle.
// (setprio removed: r11 A/B showed it costs ~4% in this barrier-locked kernel)
__global__ __launch_bounds__(256) void k_attn_mfma(
    u16* __restrict__ q, const u16* __restrict__ kv, const int* __restrict__ offs)
{
    __shared__ u16 KV[11520];        // union: K [32][328] (10496) | V^T [320][36]
    __shared__ float Ssm[32 * 33];   // padded stride
    __shared__ u16 Plds[32 * 40];
    __shared__ float mL[32], lL[32], aL[32];

    // decode swizzled linear block id: lin = j*8 + (g%8), j = (g/8)*80 + h*20 + qt
    const int lin = blockIdx.x;
    const int gLo = lin & 7;
    const int j   = lin >> 3;
    const int g   = (j / 80) * 8 + gLo;
    const int rem = j % 80;
    const int hh  = rem / 20;
    const int qt  = rem % 20;

    const int gstart = offs[g];
    const int n = offs[g + 1] - gstart;
    if (qt * 32 >= n) return;
    const int nq = min(32, n - qt * 32);
    const int t    = threadIdx.x;
    const int lane = t & 63;
    const int w    = t >> 6;
    const int qr   = w >> 1, kr = w & 1;
    const int l15  = lane & 15;
    const int l4   = lane >> 4;
    const float scale = 0.05590169943749474f;  // 1/sqrt(320)

    if (t < 32) { mL[t] = -1e30f; lL[t] = 0.f; }

    // ---- preload Q fragments (wave's 16 rows, K=320 = 10 chunks) ----
    bf16x8 qf[10];
    {
        int qrl = qt * 32 + qr * 16 + l15;
        if (qrl >= n) qrl = n - 1;
        const u16* gq = &q[(long)(gstart + qrl) * DIM + hh * DH + l4 * 8];
        #pragma unroll
        for (int c = 0; c < 10; ++c)
            qf[c] = *(const bf16x8*)&gq[c * 32];
    }

    f32x4 oacc[2][5];
    #pragma unroll
    for (int a = 0; a < 2; ++a)
        #pragma unroll
        for (int f = 0; f < 5; ++f) oacc[a][f] = (f32x4){0.f, 0.f, 0.f, 0.f};

    // staging coords
    const int spos = t >> 3;           // K: pos 0..31
    const int sfb  = (t & 7) * 40;     // K: feature base
    const int vpp  = t & 15;           // V: pos pair
    const int vfb  = (t >> 4) * 20;    // V: feature base

    for (int kb = 0; kb < n; kb += 32) {
        const int nk = min(32, n - kb);
        __syncthreads();   // [A] prev-iter KV/Plds/aL reads done

        // ---- stage K tile ----
        {
            int gp = kb + spos; if (gp >= n) gp = n - 1;
            const u16* gk = &kv[(long)(gstart + gp) * KVD + hh * DH + sfb];
            uint4 c0 = *(const uint4*)(gk + 0);
            uint4 c1 = *(const uint4*)(gk + 8);
            uint4 c2 = *(const uint4*)(gk + 16);
            uint4 c3 = *(const uint4*)(gk + 24);
            uint4 c4 = *(const uint4*)(gk + 32);
            u16* dst = &KV[spos * 328 + sfb];
            *(uint4*)(dst + 0)  = c0;
            *(uint4*)(dst + 8)  = c1;
            *(uint4*)(dst + 16) = c2;
            *(uint4*)(dst + 24) = c3;
            *(uint4*)(dst + 32) = c4;
        }
        __syncthreads();   // [B] K staged

        // ---- QK^T: wave's S quarter-tile (qr, kr) ----
        {
            f32x4 sacc = (f32x4){0.f, 0.f, 0.f, 0.f};
            #pragma unroll
            for (int c = 0; c < 10; ++c) {
                bf16x8 kf = *(const bf16x8*)&KV[(kr * 16 + l15) * 328 + c * 32 + l4 * 8];
                sacc = __builtin_amdgcn_mfma_f32_16x16x32_bf16(qf[c], kf, sacc, 0, 0, 0);
            }
            const int col = kr * 16 + l15;
            const int srow0 = qr * 16 + l4 * 4;
            const bool masked = (col >= nk);
            #pragma unroll
            for (int r = 0; r < 4; ++r)
                Ssm[(srow0 + r) * 33 + col] = masked ? -1e30f : sacc[r] * scale;
        }
        __syncthreads();   // [C] scores ready; K region dead

        // ---- softmax + V load/pack into KV (K region dead after [C]) ----
        {
            // V loads (issued here; independent of Ssm -> scheduler lifts them)
            uint2 va4[5], vb4[5];
            int p0 = kb + 2 * vpp, p1 = p0 + 1;
            if (p0 >= n) p0 = n - 1;
            if (p1 >= n) p1 = n - 1;
            const u16* g0 = &kv[(long)(gstart + p0) * KVD + DIM + hh * DH + vfb];
            const u16* g1 = &kv[(long)(gstart + p1) * KVD + DIM + hh * DH + vfb];
            #pragma unroll
            for (int i = 0; i < 5; ++i) {
                va4[i] = *(const uint2*)(g0 + i * 4);
                vb4[i] = *(const uint2*)(g1 + i * 4);
            }

            const int r  = t >> 3;
            const int cg = (t & 7) * 4;
            float4 s4 = *(const float4*)&Ssm[r * 33 + cg];
            float mx = fmaxf(fmaxf(s4.x, s4.y), fmaxf(s4.z, s4.w));
            mx = fmaxf(mx, __shfl_xor(mx, 1));
            mx = fmaxf(mx, __shfl_xor(mx, 2));
            mx = fmaxf(mx, __shfl_xor(mx, 4));
            const float mo = mL[r];
            const float mn = fmaxf(mo, mx);
            float p0f = __expf(s4.x - mn), p1f = __expf(s4.y - mn);
            float p2f = __expf(s4.z - mn), p3f = __expf(s4.w - mn);
            union { u16 h[4]; uint2 u; } pw;
            pw.h[0] = f2b(p0f); pw.h[1] = f2b(p1f); pw.h[2] = f2b(p2f); pw.h[3] = f2b(p3f);
            *(uint2*)&Plds[r * 40 + cg] = pw.u;
            float rs = p0f + p1f + p2f + p3f;
            rs += __shfl_xor(rs, 1);
            rs += __shfl_xor(rs, 2);
            rs += __shfl_xor(rs, 4);
            if ((t & 7) == 0) {
                const float al = __expf(mo - mn);
                aL[r] = al;
                lL[r] = lL[r] * al + rs;
                mL[r] = mn;
            }
            // pack V regs -> V^T layout in KV
            #pragma unroll
            for (int i = 0; i < 5; ++i) {
                const unsigned a0 = va4[i].x, a1 = va4[i].y;
                const unsigned b0 = vb4[i].x, b1 = vb4[i].y;
                const int fb = vfb + i * 4;
                *(unsigned*)&KV[(fb + 0) * 36 + 2 * vpp] = (a0 & 0xffffu) | (b0 << 16);
                *(unsigned*)&KV[(fb + 1) * 36 + 2 * vpp] = (a0 >> 16) | (b0 & 0xffff0000u);
                *(unsigned*)&KV[(fb + 2) * 36 + 2 * vpp] = (a1 & 0xffffu) | (b1 << 16);
                *(unsigned*)&KV[(fb + 3) * 36 + 2 * vpp] = (a1 >> 16) | (b1 & 0xffff0000u);
            }
        }
        __syncthreads();   // [D] P + stats + V^T ready

        // ---- PV: rescale O, then O += P @ V^T (wave's 80 feats) ----
        {
            float al[2][4];
            #pragma unroll
            for (int a = 0; a < 2; ++a)
                #pragma unroll
                for (int r = 0; r < 4; ++r)
                    al[a][r] = aL[a * 16 + l4 * 4 + r];
            #pragma unroll
            for (int a = 0; a < 2; ++a)
                #pragma unroll
                for (int f = 0; f < 5; ++f)
                    #pragma unroll
                    for (int r = 0; r < 4; ++r)
                        oacc[a][f][r] *= al[a][r];
            #pragma unroll
            for (int a = 0; a < 2; ++a) {
                bf16x8 pf = *(const bf16x8*)&Plds[(a * 16 + l15) * 40 + l4 * 8];
                #pragma unroll
                for (int f = 0; f < 5; ++f) {
                    const int fe = w * 80 + f * 16 + l15;
                    union { bf16x8 v; uint2 u[2]; } uv;
                    uv.u[0] = *(const uint2*)&KV[fe * 36 + l4 * 8];
                    uv.u[1] = *(const uint2*)&KV[fe * 36 + l4 * 8 + 4];
                    oacc[a][f] = __builtin_amdgcn_mfma_f32_16x16x32_bf16(
                        pf, uv.v, oacc[a][f], 0, 0, 0);
                }
            }
        }
    }

    // ---- epilogue ----
    float invl[2][4];
    #pragma unroll
    for (int a = 0; a < 2; ++a)
        #pragma unroll
        for (int r = 0; r < 4; ++r)
            invl[a][r] = 1.f / lL[a * 16 + l4 * 4 + r];
    #pragma unroll
    for (int a = 0; a < 2; ++a) {
        #pragma unroll
        for (int f = 0; f < 5; ++f) {
            #pragma unroll
            for (int r = 0; r < 4; ++r) {
                const int lrow = a * 16 + l4 * 4 + r;
                if (lrow < nq) {
                    const long grow = (long)(gstart + qt * 32 + lrow);
                    q[grow * DIM + hh * DH + w * 80 + f * 16 + l15] =
                        f2b(oacc[a][f][r] * invl[a][r]);
                }
            }
        }
    }
}

// ---------------- orchestration ------------------------------------------------
extern "C" void kernel_launch(void* const* d_in, const int* in_sizes, int n_in,
                              void* d_out, int out_size, void* d_ws, size_t ws_size,
                              hipStream_t stream) {
    const float* x     = (const float*)d_in[0];
    const int*   batch = (const int*)d_in[1];
    const float* Wqkv  = (const float*)d_in[2];
    const float* bqkv  = (const float*)d_in[3];
    const float* Wo    = (const float*)d_in[4];
    const float* bo    = (const float*)d_in[5];
    const float* ln1w  = (const float*)d_in[6];
    const float* ln1b  = (const float*)d_in[7];
    const float* W1    = (const float*)d_in[8];
    const float* b1    = (const float*)d_in[9];
    const float* W2    = (const float*)d_in[10];
    const float* b2    = (const float*)d_in[11];
    const float* ln2w  = (const float*)d_in[12];
    const float* ln2b  = (const float*)d_in[13];
    const float* Wm1   = (const float*)d_in[14];
    const float* bm1   = (const float*)d_in[15];
    const float* Wm2   = (const float*)d_in[16];
    const float* bm2   = (const float*)d_in[17];

    float* outF = (float*)d_out;
    u16*   qbuf = (u16*)d_out;   // first half doubles as bf16 q scratch

    char* ws   = (char*)d_ws;
    int*  offs = (int*)ws;
    u16*  h    = (u16*)(ws + 1024);
    u16*  kvb  = h + (size_t)N_TOK * DIM;
    u16*  tmp  = kvb;                           // alias, live only after attn
    u16*  ff   = kvb + (size_t)N_TOK * DIM;     // alias, disjoint from tmp
    u16*  wqkv_bf = kvb + (size_t)N_TOK * KVD;
    u16*  wo_bf   = wqkv_bf + (size_t)NLAYER * TD * DIM;
    u16*  w1_bf   = wo_bf   + (size_t)NLAYER * DIM * DIM;
    u16*  w2_bf   = w1_bf   + (size_t)NLAYER * FFD * DIM;
    u16*  wm1_bf  = w2_bf   + (size_t)NLAYER * DIM * FFD;
    u16*  wm2_bf  = wm1_bf  + (size_t)FFD * DIM;

    k_offsets<<<1, 128, 0, stream>>>(batch, offs);
    {
        long n = (long)N_TOK * DIM;
        k_f32_to_bf16<<<(int)(n / 1024), 256, 0, stream>>>(x, h, n);
        k_conv_weights<<<(int)(E5 / 1024), 256, 0, stream>>>(
            Wqkv, Wo, W1, W2, Wm1, Wm2,
            wqkv_bf, wo_bf, w1_bf, w2_bf, wm1_bf, wm2_bf);
    }

    dim3 blk(256);
    for (int l = 0; l < NLAYER; ++l) {
        const u16*   Wl = wqkv_bf + (size_t)l * TD * DIM;
        const float* bl = bqkv + (size_t)l * TD;
        // fused qkv: q -> qbuf, kv -> kvb
        k_gemm_qkv<<<dim3(TD / 128, N_TOK / 128), blk, 0, stream>>>(
            h, Wl, bl, qbuf, kvb);
        k_attn_mfma<<<dim3(20 * NH * NB), blk, 0, stream>>>(qbuf, kvb, offs);
        k_gemm_mfma<<<dim3(DIM / 128, N_TOK / 128), blk, 0, stream>>>(
            qbuf, DIM, wo_bf + (size_t)l * DIM * DIM, bo + (size_t)l * DIM,
            tmp, DIM, DIM, 0, 0);
        k_ln_residual<<<N_TOK / 4, blk, 0, stream>>>(
            h, tmp, ln1w + (size_t)l * DIM, ln1b + (size_t)l * DIM, h);
        k_gemm_mfma<<<dim3(FFD / 128, N_TOK / 128), blk, 0, stream>>>(
            h, DIM, w1_bf + (size_t)l * FFD * DIM, b1 + (size_t)l * FFD,
            ff, FFD, DIM, 1, 0);
        k_gemm_mfma<<<dim3(DIM / 128, N_TOK / 128), blk, 0, stream>>>(
            ff, FFD, w2_bf + (size_t)l * DIM * FFD, b2 + (size_t)l * DIM,
            tmp, DIM, FFD, 0, 0);
        k_ln_residual<<<N_TOK / 4, blk, 0, stream>>>(
            h, tmp, ln2w + (size_t)l * DIM, ln2b + (size_t)l * DIM, h);
    }
    k_gemm_mfma<<<dim3(FFD / 128, N_TOK / 128), blk, 0, stream>>>(
        h, DIM, wm1_bf, bm1, ff, FFD, DIM, 1, 0);
    k_gemm_mfma<<<dim3(DIM / 128, N_TOK / 128), blk, 0, stream>>>(
        ff, FFD, wm2_bf, bm2, outF, DIM, FFD, 0, 1);
}

// Round 13
// 2642.765 us; speedup vs baseline: 1.0120x; 1.0120x over previous
//
#include <hip/hip_runtime.h>

typedef unsigned short u16;
typedef __attribute__((ext_vector_type(8))) short bf16x8;
typedef __attribute__((ext_vector_type(4))) float f32x4;

#define N_TOK 32768
#define DIM   1280
#define NH    4
#define DH    320
#define FFD   256
#define NLAYER 2
#define NB    64
#define TD    3840  // 3*DIM
#define KVD   2560  // 2*DIM

#define GLD16(gp, lp) __builtin_amdgcn_global_load_lds( \
    (const __attribute__((address_space(1))) unsigned int*)(const void*)(gp), \
    (__attribute__((address_space(3))) unsigned int*)(void*)(lp), 16, 0, 0)

__device__ __forceinline__ float b2f(u16 v) {
    union { unsigned u; float f; } c; c.u = ((unsigned)v) << 16; return c.f;
}
__device__ __forceinline__ u16 f2b(float f) {
    union { float f; unsigned u; } c; c.f = f;
    unsigned r = c.u + 0x7fffu + ((c.u >> 16) & 1u);
    return (u16)(r >> 16);
}

// ---------------- f32 -> bf16 bulk convert -------------------------------------
__global__ __launch_bounds__(256) void k_f32_to_bf16(
    const float* __restrict__ in, u16* __restrict__ out, long n)
{
    long i = ((long)blockIdx.x * 256 + threadIdx.x) * 4;
    if (i >= n) return;
    float4 v = *(const float4*)&in[i];
    ushort4 o; o.x = f2b(v.x); o.y = f2b(v.y); o.z = f2b(v.z); o.w = f2b(v.w);
    *(ushort4*)&out[i] = o;
}

// ---------------- merged weight convert (6 segments, one launch) ---------------
#define E0 9830400L   // Wqkv  2*3840*1280
#define E1 13107200L  // +Wo   2*1280*1280
#define E2 13762560L  // +W1   2*256*1280
#define E3 14417920L  // +W2   2*1280*256
#define E4 14745600L  // +Wm1  256*1280
#define E5 15073280L  // +Wm2  1280*256
__global__ __launch_bounds__(256) void k_conv_weights(
    const float* __restrict__ Wqkv, const float* __restrict__ Wo,
    const float* __restrict__ W1,   const float* __restrict__ W2,
    const float* __restrict__ Wm1,  const float* __restrict__ Wm2,
    u16* __restrict__ d0, u16* __restrict__ d1, u16* __restrict__ d2,
    u16* __restrict__ d3, u16* __restrict__ d4, u16* __restrict__ d5)
{
    long i = ((long)blockIdx.x * 256 + threadIdx.x) * 4;
    if (i >= E5) return;
    const float* src; u16* dst; long off;
    if      (i < E0) { src = Wqkv; dst = d0; off = i; }
    else if (i < E1) { src = Wo;   dst = d1; off = i - E0; }
    else if (i < E2) { src = W1;   dst = d2; off = i - E1; }
    else if (i < E3) { src = W2;   dst = d3; off = i - E2; }
    else if (i < E4) { src = Wm1;  dst = d4; off = i - E3; }
    else             { src = Wm2;  dst = d5; off = i - E4; }
    float4 v = *(const float4*)&src[off];
    ushort4 o; o.x = f2b(v.x); o.y = f2b(v.y); o.z = f2b(v.z); o.w = f2b(v.w);
    *(ushort4*)&dst[off] = o;
}

// ---------------- per-graph offsets via binary search on sorted batch ----------
__global__ void k_offsets(const int* __restrict__ batch, int* __restrict__ offs) {
    int b = threadIdx.x;
    if (b > NB) return;
    int lo = 0, hi = N_TOK;
    while (lo < hi) {
        int mid = (lo + hi) >> 1;
        if (batch[mid] < b) lo = mid + 1; else hi = mid;
    }
    offs[b] = lo;   // offs[64] == N_TOK
}

// ------ MFMA GEMM: C[M,N] = A_bf16[M,K](lda) @ W_bf16[N,K]^T + bias_f32
__global__ __launch_bounds__(256) void k_gemm_mfma(
    const u16* __restrict__ A, int lda,
    const u16* __restrict__ W,
    const float* __restrict__ bias,
    void* __restrict__ Cv, int ldc,
    int K, int relu, int store_f32)
{
    __shared__ u16 Asm[128 * 64];
    __shared__ u16 Bsm[128 * 64];
    const int t    = threadIdx.x;
    const int lane = t & 63;
    const int w    = t >> 6;
    const int wr   = w >> 1, wc = w & 1;
    const long mBase = (long)blockIdx.y * 128;
    const long nBase = (long)blockIdx.x * 128;
    const int srow = lane >> 3;
    const int scol = (lane & 7) * 8;

    f32x4 acc[4][4];
    #pragma unroll
    for (int m = 0; m < 4; ++m)
        #pragma unroll
        for (int n = 0; n < 4; ++n) acc[m][n] = (f32x4){0.f, 0.f, 0.f, 0.f};

    for (int k0 = 0; k0 < K; k0 += 64) {
        __syncthreads();
        #pragma unroll
        for (int i = 0; i < 4; ++i) {
            const int c = w * 4 + i;
            const u16* ga = &A[(mBase + c * 8 + srow) * (long)lda + k0 + scol];
            const u16* gb = &W[(nBase + c * 8 + srow) * (long)K   + k0 + scol];
            GLD16(ga, &Asm[c * 512]);
            GLD16(gb, &Bsm[c * 512]);
        }
        __syncthreads();
        #pragma unroll
        for (int kk = 0; kk < 2; ++kk) {
            const int kc = kk * 32 + (lane >> 4) * 8;
            bf16x8 af[4], bfr[4];
            #pragma unroll
            for (int m = 0; m < 4; ++m)
                af[m] = *(const bf16x8*)&Asm[(wr * 64 + m * 16 + (lane & 15)) * 64 + kc];
            #pragma unroll
            for (int n = 0; n < 4; ++n)
                bfr[n] = *(const bf16x8*)&Bsm[(wc * 64 + n * 16 + (lane & 15)) * 64 + kc];
            #pragma unroll
            for (int m = 0; m < 4; ++m)
                #pragma unroll
                for (int n = 0; n < 4; ++n)
                    acc[m][n] = __builtin_amdgcn_mfma_f32_16x16x32_bf16(
                        af[m], bfr[n], acc[m][n], 0, 0, 0);
        }
    }

    const int ccol  = lane & 15;
    const int crow0 = (lane >> 4) * 4;
    #pragma unroll
    for (int m = 0; m < 4; ++m) {
        #pragma unroll
        for (int n = 0; n < 4; ++n) {
            const long col = nBase + wc * 64 + n * 16 + ccol;
            const float bv = bias[col];
            #pragma unroll
            for (int r = 0; r < 4; ++r) {
                const long row = mBase + wr * 64 + m * 16 + crow0 + r;
                float v = acc[m][n][r] + bv;
                if (relu) v = fmaxf(v, 0.f);
                if (store_f32) ((float*)Cv)[row * (long)ldc + col] = v;
                else           ((u16*)Cv)[row * (long)ldc + col] = f2b(v);
            }
        }
    }
}

// ------ fused QKV GEMM: N=3840; cols [0,1280) -> qd (ldc=DIM), rest -> kvd -----
__global__ __launch_bounds__(256) void k_gemm_qkv(
    const u16* __restrict__ A,
    const u16* __restrict__ W,
    const float* __restrict__ bias,
    u16* __restrict__ qd, u16* __restrict__ kvd)
{
    __shared__ u16 Asm[128 * 64];
    __shared__ u16 Bsm[128 * 64];
    const int t    = threadIdx.x;
    const int lane = t & 63;
    const int w    = t >> 6;
    const int wr   = w >> 1, wc = w & 1;
    const long mBase = (long)blockIdx.y * 128;
    const long nBase = (long)blockIdx.x * 128;
    const int srow = lane >> 3;
    const int scol = (lane & 7) * 8;

    f32x4 acc[4][4];
    #pragma unroll
    for (int m = 0; m < 4; ++m)
        #pragma unroll
        for (int n = 0; n < 4; ++n) acc[m][n] = (f32x4){0.f, 0.f, 0.f, 0.f};

    for (int k0 = 0; k0 < DIM; k0 += 64) {
        __syncthreads();
        #pragma unroll
        for (int i = 0; i < 4; ++i) {
            const int c = w * 4 + i;
            const u16* ga = &A[(mBase + c * 8 + srow) * (long)DIM + k0 + scol];
            const u16* gb = &W[(nBase + c * 8 + srow) * (long)DIM + k0 + scol];
            GLD16(ga, &Asm[c * 512]);
            GLD16(gb, &Bsm[c * 512]);
        }
        __syncthreads();
        #pragma unroll
        for (int kk = 0; kk < 2; ++kk) {
            const int kc = kk * 32 + (lane >> 4) * 8;
            bf16x8 af[4], bfr[4];
            #pragma unroll
            for (int m = 0; m < 4; ++m)
                af[m] = *(const bf16x8*)&Asm[(wr * 64 + m * 16 + (lane & 15)) * 64 + kc];
            #pragma unroll
            for (int n = 0; n < 4; ++n)
                bfr[n] = *(const bf16x8*)&Bsm[(wc * 64 + n * 16 + (lane & 15)) * 64 + kc];
            #pragma unroll
            for (int m = 0; m < 4; ++m)
                #pragma unroll
                for (int n = 0; n < 4; ++n)
                    acc[m][n] = __builtin_amdgcn_mfma_f32_16x16x32_bf16(
                        af[m], bfr[n], acc[m][n], 0, 0, 0);
        }
    }

    const int ccol  = lane & 15;
    const int crow0 = (lane >> 4) * 4;
    const bool isQ = (nBase < DIM);           // uniform per block (128 | 1280)
    #pragma unroll
    for (int m = 0; m < 4; ++m) {
        #pragma unroll
        for (int n = 0; n < 4; ++n) {
            const long col = nBase + wc * 64 + n * 16 + ccol;
            const float bv = bias[col];
            #pragma unroll
            for (int r = 0; r < 4; ++r) {
                const long row = mBase + wr * 64 + m * 16 + crow0 + r;
                float v = acc[m][n][r] + bv;
                if (isQ) qd[row * (long)DIM + col]          = f2b(v);
                else     kvd[row * (long)KVD + (col - DIM)] = f2b(v);
            }
        }
    }
}

// --------- fused residual + LayerNorm, wave-per-row, fully vectorized ----------
__global__ __launch_bounds__(256) void k_ln_residual(
    const u16* __restrict__ a, const u16* __restrict__ delta,
    const float* __restrict__ w, const float* __restrict__ bb,
    u16* __restrict__ out)
{
    const int lane = threadIdx.x & 63;
    const long row = (long)blockIdx.x * 4 + (threadIdx.x >> 6);
    const long base = row * DIM + lane * 20;
    float v[20];
    float s = 0.f, s2 = 0.f;
    #pragma unroll
    for (int k = 0; k < 5; ++k) {
        uint2 ua = *(const uint2*)&a[base + k * 4];
        uint2 ud = *(const uint2*)&delta[base + k * 4];
        u16 ah[4], dh[4];
        *(uint2*)ah = ua; *(uint2*)dh = ud;
        #pragma unroll
        for (int e = 0; e < 4; ++e) {
            float xv = b2f(ah[e]) + b2f(dh[e]);
            v[k * 4 + e] = xv; s += xv; s2 += xv * xv;
        }
    }
    #pragma unroll
    for (int off = 32; off > 0; off >>= 1) {
        s  += __shfl_xor(s, off);
        s2 += __shfl_xor(s2, off);
    }
    const float mu  = s * (1.f / DIM);
    const float var = s2 * (1.f / DIM) - mu * mu;
    const float inv = rsqrtf(fmaxf(var, 0.f) + 1e-5f);
    const int cb = lane * 20;
    #pragma unroll
    for (int k = 0; k < 5; ++k) {
        float4 wv = *(const float4*)&w[cb + k * 4];
        float4 bv = *(const float4*)&bb[cb + k * 4];
        u16 oh[4];
        oh[0] = f2b((v[k * 4 + 0] - mu) * inv * wv.x + bv.x);
        oh[1] = f2b((v[k * 4 + 1] - mu) * inv * wv.y + bv.y);
        oh[2] = f2b((v[k * 4 + 2] - mu) * inv * wv.z + bv.z);
        oh[3] = f2b((v[k * 4 + 3] - mu) * inv * wv.w + bv.w);
        *(uint2*)&out[base + k * 4] = *(uint2*)oh;
    }
}

// -------- MFMA flash attention, KVBLK=64: same 4-barrier skeleton as r9 but
// half the iterations (barriers per KV position halved). QBLK=32, 4 waves;
// wave (qr,kr) owns 16 rows x one 32-col half. K [64][328] / V^T [320][68]
// union LDS (43.5 KB); Ssm [32][65] f32; P [32][72] bf16. XCD swizzle.
__global__ __launch_bounds__(256) void k_attn_mfma(
    u16* __restrict__ q, const u16* __restrict__ kv, const int* __restrict__ offs)
{
    __shared__ u16 KV[21760];        // union: K 64*328 (41984B) | V^T 320*68 (43520B)
    __shared__ float Ssm[32 * 65];
    __shared__ u16 Plds[32 * 72];
    __shared__ float mL[32], lL[32], aL[32];

    // decode swizzled linear block id: lin = j*8 + (g%8), j = (g/8)*80 + h*20 + qt
    const int lin = blockIdx.x;
    const int gLo = lin & 7;
    const int j   = lin >> 3;
    const int g   = (j / 80) * 8 + gLo;
    const int rem = j % 80;
    const int hh  = rem / 20;
    const int qt  = rem % 20;

    const int gstart = offs[g];
    const int n = offs[g + 1] - gstart;
    if (qt * 32 >= n) return;
    const int nq = min(32, n - qt * 32);
    const int t    = threadIdx.x;
    const int lane = t & 63;
    const int w    = t >> 6;
    const int qr   = w >> 1, kr = w & 1;
    const int l15  = lane & 15;
    const int l4   = lane >> 4;
    const float scale = 0.05590169943749474f;  // 1/sqrt(320)

    if (t < 32) { mL[t] = -1e30f; lL[t] = 0.f; }

    // ---- preload Q fragments (wave's 16 rows, K=320 = 10 chunks) ----
    bf16x8 qf[10];
    {
        int qrl = qt * 32 + qr * 16 + l15;
        if (qrl >= n) qrl = n - 1;
        const u16* gq = &q[(long)(gstart + qrl) * DIM + hh * DH + l4 * 8];
        #pragma unroll
        for (int c = 0; c < 10; ++c)
            qf[c] = *(const bf16x8*)&gq[c * 32];
    }

    f32x4 oacc[2][5];
    #pragma unroll
    for (int a = 0; a < 2; ++a)
        #pragma unroll
        for (int f = 0; f < 5; ++f) oacc[a][f] = (f32x4){0.f, 0.f, 0.f, 0.f};

    // staging coords
    const int spos = t >> 3;           // K: pos (pass adds +32)
    const int sfb  = (t & 7) * 40;     // K: feature base
    const int vpp  = t & 15;           // V: pos pair (pass adds +16)
    const int vfb  = (t >> 4) * 20;    // V: feature base

    for (int kb = 0; kb < n; kb += 64) {
        const int nk = min(64, n - kb);
        __syncthreads();   // [A] prev-iter KV/Plds/aL reads done

        // ---- stage K tile (64 pos x 320 feats, 2 passes of r9 pattern) ----
        #pragma unroll
        for (int pass = 0; pass < 2; ++pass) {
            const int pos = spos + pass * 32;
            int gp = kb + pos; if (gp >= n) gp = n - 1;
            const u16* gk = &kv[(long)(gstart + gp) * KVD + hh * DH + sfb];
            uint4 c0 = *(const uint4*)(gk + 0);
            uint4 c1 = *(const uint4*)(gk + 8);
            uint4 c2 = *(const uint4*)(gk + 16);
            uint4 c3 = *(const uint4*)(gk + 24);
            uint4 c4 = *(const uint4*)(gk + 32);
            u16* dst = &KV[pos * 328 + sfb];
            *(uint4*)(dst + 0)  = c0;
            *(uint4*)(dst + 8)  = c1;
            *(uint4*)(dst + 16) = c2;
            *(uint4*)(dst + 24) = c3;
            *(uint4*)(dst + 32) = c4;
        }
        __syncthreads();   // [B] K staged

        // ---- QK^T: wave's 16 rows x 32-col half (2 x 16-col MFMA tiles) ----
        #pragma unroll
        for (int kk = 0; kk < 2; ++kk) {
            const int colb = kr * 32 + kk * 16;
            f32x4 sacc = (f32x4){0.f, 0.f, 0.f, 0.f};
            #pragma unroll
            for (int c = 0; c < 10; ++c) {
                bf16x8 kf = *(const bf16x8*)&KV[(colb + l15) * 328 + c * 32 + l4 * 8];
                sacc = __builtin_amdgcn_mfma_f32_16x16x32_bf16(qf[c], kf, sacc, 0, 0, 0);
            }
            const int col = colb + l15;
            const int srow0 = qr * 16 + l4 * 4;
            const bool masked = (col >= nk);
            #pragma unroll
            for (int r = 0; r < 4; ++r)
                Ssm[(srow0 + r) * 65 + col] = masked ? -1e30f : sacc[r] * scale;
        }
        __syncthreads();   // [C] scores ready; K region dead

        // ---- softmax (8 cols/lane) + V load/pack into KV (V^T, stride 68) ----
        {
            uint2 va4[2][5], vb4[2][5];
            #pragma unroll
            for (int pass = 0; pass < 2; ++pass) {
                int pr = vpp + pass * 16;
                int p0 = kb + 2 * pr, p1 = p0 + 1;
                if (p0 >= n) p0 = n - 1;
                if (p1 >= n) p1 = n - 1;
                const u16* g0 = &kv[(long)(gstart + p0) * KVD + DIM + hh * DH + vfb];
                const u16* g1 = &kv[(long)(gstart + p1) * KVD + DIM + hh * DH + vfb];
                #pragma unroll
                for (int i = 0; i < 5; ++i) {
                    va4[pass][i] = *(const uint2*)(g0 + i * 4);
                    vb4[pass][i] = *(const uint2*)(g1 + i * 4);
                }
            }

            const int r  = t >> 3;
            const int cg = (t & 7) * 8;
            float4 sa = *(const float4*)&Ssm[r * 65 + cg];
            float4 sb = *(const float4*)&Ssm[r * 65 + cg + 4];
            float mx = fmaxf(fmaxf(fmaxf(sa.x, sa.y), fmaxf(sa.z, sa.w)),
                             fmaxf(fmaxf(sb.x, sb.y), fmaxf(sb.z, sb.w)));
            mx = fmaxf(mx, __shfl_xor(mx, 1));
            mx = fmaxf(mx, __shfl_xor(mx, 2));
            mx = fmaxf(mx, __shfl_xor(mx, 4));
            const float mo = mL[r];
            const float mn = fmaxf(mo, mx);
            float p0f = __expf(sa.x - mn), p1f = __expf(sa.y - mn);
            float p2f = __expf(sa.z - mn), p3f = __expf(sa.w - mn);
            float p4f = __expf(sb.x - mn), p5f = __expf(sb.y - mn);
            float p6f = __expf(sb.z - mn), p7f = __expf(sb.w - mn);
            union { u16 h[8]; uint4 u; } pw;
            pw.h[0] = f2b(p0f); pw.h[1] = f2b(p1f); pw.h[2] = f2b(p2f); pw.h[3] = f2b(p3f);
            pw.h[4] = f2b(p4f); pw.h[5] = f2b(p5f); pw.h[6] = f2b(p6f); pw.h[7] = f2b(p7f);
            *(uint4*)&Plds[r * 72 + cg] = pw.u;
            float rs = ((p0f + p1f) + (p2f + p3f)) + ((p4f + p5f) + (p6f + p7f));
            rs += __shfl_xor(rs, 1);
            rs += __shfl_xor(rs, 2);
            rs += __shfl_xor(rs, 4);
            if ((t & 7) == 0) {
                const float al = __expf(mo - mn);
                aL[r] = al;
                lL[r] = lL[r] * al + rs;
                mL[r] = mn;
            }
            // pack V regs -> V^T layout in KV (stride 68)
            #pragma unroll
            for (int pass = 0; pass < 2; ++pass) {
                const int colp = 2 * (vpp + pass * 16);
                #pragma unroll
                for (int i = 0; i < 5; ++i) {
                    const unsigned a0 = va4[pass][i].x, a1 = va4[pass][i].y;
                    const unsigned b0 = vb4[pass][i].x, b1 = vb4[pass][i].y;
                    const int fb = vfb + i * 4;
                    *(unsigned*)&KV[(fb + 0) * 68 + colp] = (a0 & 0xffffu) | (b0 << 16);
                    *(unsigned*)&KV[(fb + 1) * 68 + colp] = (a0 >> 16) | (b0 & 0xffff0000u);
                    *(unsigned*)&KV[(fb + 2) * 68 + colp] = (a1 & 0xffffu) | (b1 << 16);
                    *(unsigned*)&KV[(fb + 3) * 68 + colp] = (a1 >> 16) | (b1 & 0xffff0000u);
                }
            }
        }
        __syncthreads();   // [D] P + stats + V^T ready

        // ---- PV: rescale O once, then O += P @ V^T over 2 k-slots ----
        {
            float al[2][4];
            #pragma unroll
            for (int a = 0; a < 2; ++a)
                #pragma unroll
                for (int r = 0; r < 4; ++r)
                    al[a][r] = aL[a * 16 + l4 * 4 + r];
            #pragma unroll
            for (int a = 0; a < 2; ++a)
                #pragma unroll
                for (int f = 0; f < 5; ++f)
                    #pragma unroll
                    for (int r = 0; r < 4; ++r)
                        oacc[a][f][r] *= al[a][r];
            #pragma unroll
            for (int ks = 0; ks < 2; ++ks) {
                #pragma unroll
                for (int a = 0; a < 2; ++a) {
                    bf16x8 pf = *(const bf16x8*)&Plds[(a * 16 + l15) * 72 + ks * 32 + l4 * 8];
                    #pragma unroll
                    for (int f = 0; f < 5; ++f) {
                        const int fe = w * 80 + f * 16 + l15;
                        union { bf16x8 v; uint2 u[2]; } uv;
                        uv.u[0] = *(const uint2*)&KV[fe * 68 + ks * 32 + l4 * 8];
                        uv.u[1] = *(const uint2*)&KV[fe * 68 + ks * 32 + l4 * 8 + 4];
                        oacc[a][f] = __builtin_amdgcn_mfma_f32_16x16x32_bf16(
                            pf, uv.v, oacc[a][f], 0, 0, 0);
                    }
                }
            }
        }
    }

    // ---- epilogue ----
    float invl[2][4];
    #pragma unroll
    for (int a = 0; a < 2; ++a)
        #pragma unroll
        for (int r = 0; r < 4; ++r)
            invl[a][r] = 1.f / lL[a * 16 + l4 * 4 + r];
    #pragma unroll
    for (int a = 0; a < 2; ++a) {
        #pragma unroll
        for (int f = 0; f < 5; ++f) {
            #pragma unroll
            for (int r = 0; r < 4; ++r) {
                const int lrow = a * 16 + l4 * 4 + r;
                if (lrow < nq) {
                    const long grow = (long)(gstart + qt * 32 + lrow);
                    q[grow * DIM + hh * DH + w * 80 + f * 16 + l15] =
                        f2b(oacc[a][f][r] * invl[a][r]);
                }
            }
        }
    }
}

// ---------------- orchestration ------------------------------------------------
extern "C" void kernel_launch(void* const* d_in, const int* in_sizes, int n_in,
                              void* d_out, int out_size, void* d_ws, size_t ws_size,
                              hipStream_t stream) {
    const float* x     = (const float*)d_in[0];
    const int*   batch = (const int*)d_in[1];
    const float* Wqkv  = (const float*)d_in[2];
    const float* bqkv  = (const float*)d_in[3];
    const float* Wo    = (const float*)d_in[4];
    const float* bo    = (const float*)d_in[5];
    const float* ln1w  = (const float*)d_in[6];
    const float* ln1b  = (const float*)d_in[7];
    const float* W1    = (const float*)d_in[8];
    const float* b1    = (const float*)d_in[9];
    const float* W2    = (const float*)d_in[10];
    const float* b2    = (const float*)d_in[11];
    const float* ln2w  = (const float*)d_in[12];
    const float* ln2b  = (const float*)d_in[13];
    const float* Wm1   = (const float*)d_in[14];
    const float* bm1   = (const float*)d_in[15];
    const float* Wm2   = (const float*)d_in[16];
    const float* bm2   = (const float*)d_in[17];

    float* outF = (float*)d_out;
    u16*   qbuf = (u16*)d_out;   // first half doubles as bf16 q scratch

    char* ws   = (char*)d_ws;
    int*  offs = (int*)ws;
    u16*  h    = (u16*)(ws + 1024);
    u16*  kvb  = h + (size_t)N_TOK * DIM;
    u16*  tmp  = kvb;                           // alias, live only after attn
    u16*  ff   = kvb + (size_t)N_TOK * DIM;     // alias, disjoint from tmp
    u16*  wqkv_bf = kvb + (size_t)N_TOK * KVD;
    u16*  wo_bf   = wqkv_bf + (size_t)NLAYER * TD * DIM;
    u16*  w1_bf   = wo_bf   + (size_t)NLAYER * DIM * DIM;
    u16*  w2_bf   = w1_bf   + (size_t)NLAYER * FFD * DIM;
    u16*  wm1_bf  = w2_bf   + (size_t)NLAYER * DIM * FFD;
    u16*  wm2_bf  = wm1_bf  + (size_t)FFD * DIM;

    k_offsets<<<1, 128, 0, stream>>>(batch, offs);
    {
        long n = (long)N_TOK * DIM;
        k_f32_to_bf16<<<(int)(n / 1024), 256, 0, stream>>>(x, h, n);
        k_conv_weights<<<(int)(E5 / 1024), 256, 0, stream>>>(
            Wqkv, Wo, W1, W2, Wm1, Wm2,
            wqkv_bf, wo_bf, w1_bf, w2_bf, wm1_bf, wm2_bf);
    }

    dim3 blk(256);
    for (int l = 0; l < NLAYER; ++l) {
        const u16*   Wl = wqkv_bf + (size_t)l * TD * DIM;
        const float* bl = bqkv + (size_t)l * TD;
        // fused qkv: q -> qbuf, kv -> kvb
        k_gemm_qkv<<<dim3(TD / 128, N_TOK / 128), blk, 0, stream>>>(
            h, Wl, bl, qbuf, kvb);
        k_attn_mfma<<<dim3(20 * NH * NB), blk, 0, stream>>>(qbuf, kvb, offs);
        k_gemm_mfma<<<dim3(DIM / 128, N_TOK / 128), blk, 0, stream>>>(
            qbuf, DIM, wo_bf + (size_t)l * DIM * DIM, bo + (size_t)l * DIM,
            tmp, DIM, DIM, 0, 0);
        k_ln_residual<<<N_TOK / 4, blk, 0, stream>>>(
            h, tmp, ln1w + (size_t)l * DIM, ln1b + (size_t)l * DIM, h);
        k_gemm_mfma<<<dim3(FFD / 128, N_TOK / 128), blk, 0, stream>>>(
            h, DIM, w1_bf + (size_t)l * FFD * DIM, b1 + (size_t)l * FFD,
            ff, FFD, DIM, 1, 0);
        k_gemm_mfma<<<dim3(DIM / 128, N_TOK / 128), blk, 0, stream>>>(
            ff, FFD, w2_bf + (size_t)l * DIM * FFD, b2 + (size_t)l * DIM,
            tmp, DIM, FFD, 0, 0);
        k_ln_residual<<<N_TOK / 4, blk, 0, stream>>>(
            h, tmp, ln2w + (size_t)l * DIM, ln2b + (size_t)l * DIM, h);
    }
    k_gemm_mfma<<<dim3(FFD / 128, N_TOK / 128), blk, 0, stream>>>(
        h, DIM, wm1_bf, bm1, ff, FFD, DIM, 1, 0);
    k_gemm_mfma<<<dim3(DIM / 128, N_TOK / 128), blk, 0, stream>>>(
        ff, FFD, wm2_bf, bm2, outF, DIM, FFD, 0, 1);
}

// Round 14
// 2573.056 us; speedup vs baseline: 1.0394x; 1.0271x over previous
//
#include <hip/hip_runtime.h>

typedef unsigned short u16;
typedef __attribute__((ext_vector_type(8))) short bf16x8;
typedef __attribute__((ext_vector_type(4))) float f32x4;

#define N_TOK 32768
#define DIM   1280
#define NH    4
#define DH    320
#define FFD   256
#define NLAYER 2
#define NB    64
#define TD    3840  // 3*DIM
#define KVD   2560  // 2*DIM

#define GLD16(gp, lp) __builtin_amdgcn_global_load_lds( \
    (const __attribute__((address_space(1))) unsigned int*)(const void*)(gp), \
    (__attribute__((address_space(3))) unsigned int*)(void*)(lp), 16, 0, 0)

__device__ __forceinline__ float b2f(u16 v) {
    union { unsigned u; float f; } c; c.u = ((unsigned)v) << 16; return c.f;
}
__device__ __forceinline__ u16 f2b(float f) {
    union { float f; unsigned u; } c; c.f = f;
    unsigned r = c.u + 0x7fffu + ((c.u >> 16) & 1u);
    return (u16)(r >> 16);
}

// ---------------- f32 -> bf16 bulk convert -------------------------------------
__global__ __launch_bounds__(256) void k_f32_to_bf16(
    const float* __restrict__ in, u16* __restrict__ out, long n)
{
    long i = ((long)blockIdx.x * 256 + threadIdx.x) * 4;
    if (i >= n) return;
    float4 v = *(const float4*)&in[i];
    ushort4 o; o.x = f2b(v.x); o.y = f2b(v.y); o.z = f2b(v.z); o.w = f2b(v.w);
    *(ushort4*)&out[i] = o;
}

// ---------------- merged weight convert (6 segments, one launch) ---------------
#define E0 9830400L   // Wqkv  2*3840*1280
#define E1 13107200L  // +Wo   2*1280*1280
#define E2 13762560L  // +W1   2*256*1280
#define E3 14417920L  // +W2   2*1280*256
#define E4 14745600L  // +Wm1  256*1280
#define E5 15073280L  // +Wm2  1280*256
__global__ __launch_bounds__(256) void k_conv_weights(
    const float* __restrict__ Wqkv, const float* __restrict__ Wo,
    const float* __restrict__ W1,   const float* __restrict__ W2,
    const float* __restrict__ Wm1,  const float* __restrict__ Wm2,
    u16* __restrict__ d0, u16* __restrict__ d1, u16* __restrict__ d2,
    u16* __restrict__ d3, u16* __restrict__ d4, u16* __restrict__ d5)
{
    long i = ((long)blockIdx.x * 256 + threadIdx.x) * 4;
    if (i >= E5) return;
    const float* src; u16* dst; long off;
    if      (i < E0) { src = Wqkv; dst = d0; off = i; }
    else if (i < E1) { src = Wo;   dst = d1; off = i - E0; }
    else if (i < E2) { src = W1;   dst = d2; off = i - E1; }
    else if (i < E3) { src = W2;   dst = d3; off = i - E2; }
    else if (i < E4) { src = Wm1;  dst = d4; off = i - E3; }
    else             { src = Wm2;  dst = d5; off = i - E4; }
    float4 v = *(const float4*)&src[off];
    ushort4 o; o.x = f2b(v.x); o.y = f2b(v.y); o.z = f2b(v.z); o.w = f2b(v.w);
    *(ushort4*)&dst[off] = o;
}

// ---------------- per-graph offsets via binary search on sorted batch ----------
__global__ void k_offsets(const int* __restrict__ batch, int* __restrict__ offs) {
    int b = threadIdx.x;
    if (b > NB) return;
    int lo = 0, hi = N_TOK;
    while (lo < hi) {
        int mid = (lo + hi) >> 1;
        if (batch[mid] < b) lo = mid + 1; else hi = mid;
    }
    offs[b] = lo;   // offs[64] == N_TOK
}

// ------ MFMA GEMM: C[M,N] = A_bf16[M,K](lda) @ W_bf16[N,K]^T + bias_f32
__global__ __launch_bounds__(256) void k_gemm_mfma(
    const u16* __restrict__ A, int lda,
    const u16* __restrict__ W,
    const float* __restrict__ bias,
    void* __restrict__ Cv, int ldc,
    int K, int relu, int store_f32)
{
    __shared__ u16 Asm[128 * 64];
    __shared__ u16 Bsm[128 * 64];
    const int t    = threadIdx.x;
    const int lane = t & 63;
    const int w    = t >> 6;
    const int wr   = w >> 1, wc = w & 1;
    const long mBase = (long)blockIdx.y * 128;
    const long nBase = (long)blockIdx.x * 128;
    const int srow = lane >> 3;
    const int scol = (lane & 7) * 8;

    f32x4 acc[4][4];
    #pragma unroll
    for (int m = 0; m < 4; ++m)
        #pragma unroll
        for (int n = 0; n < 4; ++n) acc[m][n] = (f32x4){0.f, 0.f, 0.f, 0.f};

    for (int k0 = 0; k0 < K; k0 += 64) {
        __syncthreads();
        #pragma unroll
        for (int i = 0; i < 4; ++i) {
            const int c = w * 4 + i;
            const u16* ga = &A[(mBase + c * 8 + srow) * (long)lda + k0 + scol];
            const u16* gb = &W[(nBase + c * 8 + srow) * (long)K   + k0 + scol];
            GLD16(ga, &Asm[c * 512]);
            GLD16(gb, &Bsm[c * 512]);
        }
        __syncthreads();
        #pragma unroll
        for (int kk = 0; kk < 2; ++kk) {
            const int kc = kk * 32 + (lane >> 4) * 8;
            bf16x8 af[4], bfr[4];
            #pragma unroll
            for (int m = 0; m < 4; ++m)
                af[m] = *(const bf16x8*)&Asm[(wr * 64 + m * 16 + (lane & 15)) * 64 + kc];
            #pragma unroll
            for (int n = 0; n < 4; ++n)
                bfr[n] = *(const bf16x8*)&Bsm[(wc * 64 + n * 16 + (lane & 15)) * 64 + kc];
            #pragma unroll
            for (int m = 0; m < 4; ++m)
                #pragma unroll
                for (int n = 0; n < 4; ++n)
                    acc[m][n] = __builtin_amdgcn_mfma_f32_16x16x32_bf16(
                        af[m], bfr[n], acc[m][n], 0, 0, 0);
        }
    }

    const int ccol  = lane & 15;
    const int crow0 = (lane >> 4) * 4;
    #pragma unroll
    for (int m = 0; m < 4; ++m) {
        #pragma unroll
        for (int n = 0; n < 4; ++n) {
            const long col = nBase + wc * 64 + n * 16 + ccol;
            const float bv = bias[col];
            #pragma unroll
            for (int r = 0; r < 4; ++r) {
                const long row = mBase + wr * 64 + m * 16 + crow0 + r;
                float v = acc[m][n][r] + bv;
                if (relu) v = fmaxf(v, 0.f);
                if (store_f32) ((float*)Cv)[row * (long)ldc + col] = v;
                else           ((u16*)Cv)[row * (long)ldc + col] = f2b(v);
            }
        }
    }
}

// ------ fused QKV GEMM: N=3840; cols [0,1280) -> qd (ldc=DIM), rest -> kvd -----
__global__ __launch_bounds__(256) void k_gemm_qkv(
    const u16* __restrict__ A,
    const u16* __restrict__ W,
    const float* __restrict__ bias,
    u16* __restrict__ qd, u16* __restrict__ kvd)
{
    __shared__ u16 Asm[128 * 64];
    __shared__ u16 Bsm[128 * 64];
    const int t    = threadIdx.x;
    const int lane = t & 63;
    const int w    = t >> 6;
    const int wr   = w >> 1, wc = w & 1;
    const long mBase = (long)blockIdx.y * 128;
    const long nBase = (long)blockIdx.x * 128;
    const int srow = lane >> 3;
    const int scol = (lane & 7) * 8;

    f32x4 acc[4][4];
    #pragma unroll
    for (int m = 0; m < 4; ++m)
        #pragma unroll
        for (int n = 0; n < 4; ++n) acc[m][n] = (f32x4){0.f, 0.f, 0.f, 0.f};

    for (int k0 = 0; k0 < DIM; k0 += 64) {
        __syncthreads();
        #pragma unroll
        for (int i = 0; i < 4; ++i) {
            const int c = w * 4 + i;
            const u16* ga = &A[(mBase + c * 8 + srow) * (long)DIM + k0 + scol];
            const u16* gb = &W[(nBase + c * 8 + srow) * (long)DIM + k0 + scol];
            GLD16(ga, &Asm[c * 512]);
            GLD16(gb, &Bsm[c * 512]);
        }
        __syncthreads();
        #pragma unroll
        for (int kk = 0; kk < 2; ++kk) {
            const int kc = kk * 32 + (lane >> 4) * 8;
            bf16x8 af[4], bfr[4];
            #pragma unroll
            for (int m = 0; m < 4; ++m)
                af[m] = *(const bf16x8*)&Asm[(wr * 64 + m * 16 + (lane & 15)) * 64 + kc];
            #pragma unroll
            for (int n = 0; n < 4; ++n)
                bfr[n] = *(const bf16x8*)&Bsm[(wc * 64 + n * 16 + (lane & 15)) * 64 + kc];
            #pragma unroll
            for (int m = 0; m < 4; ++m)
                #pragma unroll
                for (int n = 0; n < 4; ++n)
                    acc[m][n] = __builtin_amdgcn_mfma_f32_16x16x32_bf16(
                        af[m], bfr[n], acc[m][n], 0, 0, 0);
        }
    }

    const int ccol  = lane & 15;
    const int crow0 = (lane >> 4) * 4;
    const bool isQ = (nBase < DIM);           // uniform per block (128 | 1280)
    #pragma unroll
    for (int m = 0; m < 4; ++m) {
        #pragma unroll
        for (int n = 0; n < 4; ++n) {
            const long col = nBase + wc * 64 + n * 16 + ccol;
            const float bv = bias[col];
            #pragma unroll
            for (int r = 0; r < 4; ++r) {
                const long row = mBase + wr * 64 + m * 16 + crow0 + r;
                float v = acc[m][n][r] + bv;
                if (isQ) qd[row * (long)DIM + col]          = f2b(v);
                else     kvd[row * (long)KVD + (col - DIM)] = f2b(v);
            }
        }
    }
}

// --------- fused residual + LayerNorm, wave-per-row, fully vectorized ----------
__global__ __launch_bounds__(256) void k_ln_residual(
    const u16* __restrict__ a, const u16* __restrict__ delta,
    const float* __restrict__ w, const float* __restrict__ bb,
    u16* __restrict__ out)
{
    const int lane = threadIdx.x & 63;
    const long row = (long)blockIdx.x * 4 + (threadIdx.x >> 6);
    const long base = row * DIM + lane * 20;
    float v[20];
    float s = 0.f, s2 = 0.f;
    #pragma unroll
    for (int k = 0; k < 5; ++k) {
        uint2 ua = *(const uint2*)&a[base + k * 4];
        uint2 ud = *(const uint2*)&delta[base + k * 4];
        u16 ah[4], dh[4];
        *(uint2*)ah = ua; *(uint2*)dh = ud;
        #pragma unroll
        for (int e = 0; e < 4; ++e) {
            float xv = b2f(ah[e]) + b2f(dh[e]);
            v[k * 4 + e] = xv; s += xv; s2 += xv * xv;
        }
    }
    #pragma unroll
    for (int off = 32; off > 0; off >>= 1) {
        s  += __shfl_xor(s, off);
        s2 += __shfl_xor(s2, off);
    }
    const float mu  = s * (1.f / DIM);
    const float var = s2 * (1.f / DIM) - mu * mu;
    const float inv = rsqrtf(fmaxf(var, 0.f) + 1e-5f);
    const int cb = lane * 20;
    #pragma unroll
    for (int k = 0; k < 5; ++k) {
        float4 wv = *(const float4*)&w[cb + k * 4];
        float4 bv = *(const float4*)&bb[cb + k * 4];
        u16 oh[4];
        oh[0] = f2b((v[k * 4 + 0] - mu) * inv * wv.x + bv.x);
        oh[1] = f2b((v[k * 4 + 1] - mu) * inv * wv.y + bv.y);
        oh[2] = f2b((v[k * 4 + 2] - mu) * inv * wv.z + bv.z);
        oh[3] = f2b((v[k * 4 + 3] - mu) * inv * wv.w + bv.w);
        *(uint2*)&out[base + k * 4] = *(uint2*)oh;
    }
}

// -------- MFMA flash attention, QBLK=64 x 8 waves (512 thr), KVBLK=64.
// QK^T: wave (qr=w>>1, kr=w&1) -> 16 rows x 32 cols. PV: wave (rh=w>>2, fs=w&3)
// -> 32 rows x 80 feats. K staged once per 64 Q-rows (halved staging traffic);
// LDS ~70KB -> 2 blocks/CU = 16 waves/CU (2x concurrency vs r13).
__global__ __launch_bounds__(512) void k_attn_mfma(
    u16* __restrict__ q, const u16* __restrict__ kv, const int* __restrict__ offs)
{
    __shared__ u16 KV[21760];        // union: K 64*328 (41984B) | V^T 320*68 (43520B)
    __shared__ float Ssm[64 * 65];
    __shared__ u16 Plds[64 * 72];
    __shared__ float mL[64], lL[64], aL[64];

    // decode swizzled linear block id: lin = j*8 + (g%8), j = (g/8)*40 + h*10 + qt
    const int lin = blockIdx.x;
    const int gLo = lin & 7;
    const int j   = lin >> 3;
    const int g   = (j / 40) * 8 + gLo;
    const int rem = j % 40;
    const int hh  = rem / 10;
    const int qt  = rem % 10;

    const int gstart = offs[g];
    const int n = offs[g + 1] - gstart;
    if (qt * 64 >= n) return;
    const int nq = min(64, n - qt * 64);
    const int t    = threadIdx.x;
    const int lane = t & 63;
    const int w    = t >> 6;
    const int qr   = w >> 1, kr = w & 1;   // QK^T split
    const int rh   = w >> 2, fs = w & 3;   // PV split
    const int l15  = lane & 15;
    const int l4   = lane >> 4;
    const float scale = 0.05590169943749474f;  // 1/sqrt(320)

    if (t < 64) { mL[t] = -1e30f; lL[t] = 0.f; }

    // ---- preload Q fragments (wave's 16 rows, K=320 = 10 chunks) ----
    bf16x8 qf[10];
    {
        int qrl = qt * 64 + qr * 16 + l15;
        if (qrl >= n) qrl = n - 1;
        const u16* gq = &q[(long)(gstart + qrl) * DIM + hh * DH + l4 * 8];
        #pragma unroll
        for (int c = 0; c < 10; ++c)
            qf[c] = *(const bf16x8*)&gq[c * 32];
    }

    f32x4 oacc[2][5];
    #pragma unroll
    for (int a = 0; a < 2; ++a)
        #pragma unroll
        for (int f = 0; f < 5; ++f) oacc[a][f] = (f32x4){0.f, 0.f, 0.f, 0.f};

    // staging coords (512 threads)
    const int spos = t >> 3;           // K: pos 0..63
    const int sfb  = (t & 7) * 40;     // K: feature base
    const int vpp  = t & 31;           // V: pos pair 0..31
    const int vfb  = (t >> 5) * 20;    // V: feature base 0..300

    for (int kb = 0; kb < n; kb += 64) {
        const int nk = min(64, n - kb);
        __syncthreads();   // [A] prev-iter KV/Plds/aL reads done

        // ---- stage K tile (64 pos x 320 feats, single pass) ----
        {
            int gp = kb + spos; if (gp >= n) gp = n - 1;
            const u16* gk = &kv[(long)(gstart + gp) * KVD + hh * DH + sfb];
            uint4 c0 = *(const uint4*)(gk + 0);
            uint4 c1 = *(const uint4*)(gk + 8);
            uint4 c2 = *(const uint4*)(gk + 16);
            uint4 c3 = *(const uint4*)(gk + 24);
            uint4 c4 = *(const uint4*)(gk + 32);
            u16* dst = &KV[spos * 328 + sfb];
            *(uint4*)(dst + 0)  = c0;
            *(uint4*)(dst + 8)  = c1;
            *(uint4*)(dst + 16) = c2;
            *(uint4*)(dst + 24) = c3;
            *(uint4*)(dst + 32) = c4;
        }
        __syncthreads();   // [B] K staged

        // ---- QK^T: wave's 16 rows x 32-col half (2 x 16-col MFMA tiles) ----
        #pragma unroll
        for (int kk = 0; kk < 2; ++kk) {
            const int colb = kr * 32 + kk * 16;
            f32x4 sacc = (f32x4){0.f, 0.f, 0.f, 0.f};
            #pragma unroll
            for (int c = 0; c < 10; ++c) {
                bf16x8 kf = *(const bf16x8*)&KV[(colb + l15) * 328 + c * 32 + l4 * 8];
                sacc = __builtin_amdgcn_mfma_f32_16x16x32_bf16(qf[c], kf, sacc, 0, 0, 0);
            }
            const int col = colb + l15;
            const int srow0 = qr * 16 + l4 * 4;
            const bool masked = (col >= nk);
            #pragma unroll
            for (int r = 0; r < 4; ++r)
                Ssm[(srow0 + r) * 65 + col] = masked ? -1e30f : sacc[r] * scale;
        }
        __syncthreads();   // [C] scores ready; K region dead

        // ---- softmax (row r=t>>3, 8 cols/lane) + V load/pack (V^T, stride 68) --
        {
            uint2 va4[5], vb4[5];
            {
                int p0 = kb + 2 * vpp, p1 = p0 + 1;
                if (p0 >= n) p0 = n - 1;
                if (p1 >= n) p1 = n - 1;
                const u16* g0 = &kv[(long)(gstart + p0) * KVD + DIM + hh * DH + vfb];
                const u16* g1 = &kv[(long)(gstart + p1) * KVD + DIM + hh * DH + vfb];
                #pragma unroll
                for (int i = 0; i < 5; ++i) {
                    va4[i] = *(const uint2*)(g0 + i * 4);
                    vb4[i] = *(const uint2*)(g1 + i * 4);
                }
            }

            const int r  = t >> 3;
            const int cg = (t & 7) * 8;
            float4 sa = *(const float4*)&Ssm[r * 65 + cg];
            float4 sb = *(const float4*)&Ssm[r * 65 + cg + 4];
            float mx = fmaxf(fmaxf(fmaxf(sa.x, sa.y), fmaxf(sa.z, sa.w)),
                             fmaxf(fmaxf(sb.x, sb.y), fmaxf(sb.z, sb.w)));
            mx = fmaxf(mx, __shfl_xor(mx, 1));
            mx = fmaxf(mx, __shfl_xor(mx, 2));
            mx = fmaxf(mx, __shfl_xor(mx, 4));
            const float mo = mL[r];
            const float mn = fmaxf(mo, mx);
            float p0f = __expf(sa.x - mn), p1f = __expf(sa.y - mn);
            float p2f = __expf(sa.z - mn), p3f = __expf(sa.w - mn);
            float p4f = __expf(sb.x - mn), p5f = __expf(sb.y - mn);
            float p6f = __expf(sb.z - mn), p7f = __expf(sb.w - mn);
            union { u16 h[8]; uint4 u; } pw;
            pw.h[0] = f2b(p0f); pw.h[1] = f2b(p1f); pw.h[2] = f2b(p2f); pw.h[3] = f2b(p3f);
            pw.h[4] = f2b(p4f); pw.h[5] = f2b(p5f); pw.h[6] = f2b(p6f); pw.h[7] = f2b(p7f);
            *(uint4*)&Plds[r * 72 + cg] = pw.u;
            float rs = ((p0f + p1f) + (p2f + p3f)) + ((p4f + p5f) + (p6f + p7f));
            rs += __shfl_xor(rs, 1);
            rs += __shfl_xor(rs, 2);
            rs += __shfl_xor(rs, 4);
            if ((t & 7) == 0) {
                const float al = __expf(mo - mn);
                aL[r] = al;
                lL[r] = lL[r] * al + rs;
                mL[r] = mn;
            }
            // pack V regs -> V^T layout in KV (stride 68)
            {
                const int colp = 2 * vpp;
                #pragma unroll
                for (int i = 0; i < 5; ++i) {
                    const unsigned a0 = va4[i].x, a1 = va4[i].y;
                    const unsigned b0 = vb4[i].x, b1 = vb4[i].y;
                    const int fb = vfb + i * 4;
                    *(unsigned*)&KV[(fb + 0) * 68 + colp] = (a0 & 0xffffu) | (b0 << 16);
                    *(unsigned*)&KV[(fb + 1) * 68 + colp] = (a0 >> 16) | (b0 & 0xffff0000u);
                    *(unsigned*)&KV[(fb + 2) * 68 + colp] = (a1 & 0xffffu) | (b1 << 16);
                    *(unsigned*)&KV[(fb + 3) * 68 + colp] = (a1 >> 16) | (b1 & 0xffff0000u);
                }
            }
        }
        __syncthreads();   // [D] P + stats + V^T ready

        // ---- PV: rescale O, then O += P @ V^T (wave: 32 rows x 80 feats) ----
        {
            float al[2][4];
            #pragma unroll
            for (int a = 0; a < 2; ++a)
                #pragma unroll
                for (int r = 0; r < 4; ++r)
                    al[a][r] = aL[rh * 32 + a * 16 + l4 * 4 + r];
            #pragma unroll
            for (int a = 0; a < 2; ++a)
                #pragma unroll
                for (int f = 0; f < 5; ++f)
                    #pragma unroll
                    for (int r = 0; r < 4; ++r)
                        oacc[a][f][r] *= al[a][r];
            #pragma unroll
            for (int ks = 0; ks < 2; ++ks) {
                #pragma unroll
                for (int a = 0; a < 2; ++a) {
                    bf16x8 pf = *(const bf16x8*)&Plds[(rh * 32 + a * 16 + l15) * 72 + ks * 32 + l4 * 8];
                    #pragma unroll
                    for (int f = 0; f < 5; ++f) {
                        const int fe = fs * 80 + f * 16 + l15;
                        union { bf16x8 v; uint2 u[2]; } uv;
                        uv.u[0] = *(const uint2*)&KV[fe * 68 + ks * 32 + l4 * 8];
                        uv.u[1] = *(const uint2*)&KV[fe * 68 + ks * 32 + l4 * 8 + 4];
                        oacc[a][f] = __builtin_amdgcn_mfma_f32_16x16x32_bf16(
                            pf, uv.v, oacc[a][f], 0, 0, 0);
                    }
                }
            }
        }
    }

    // ---- epilogue: wave stores its 32 rows x 80 feats ----
    float invl[2][4];
    #pragma unroll
    for (int a = 0; a < 2; ++a)
        #pragma unroll
        for (int r = 0; r < 4; ++r)
            invl[a][r] = 1.f / lL[rh * 32 + a * 16 + l4 * 4 + r];
    #pragma unroll
    for (int a = 0; a < 2; ++a) {
        #pragma unroll
        for (int f = 0; f < 5; ++f) {
            #pragma unroll
            for (int r = 0; r < 4; ++r) {
                const int lrow = rh * 32 + a * 16 + l4 * 4 + r;
                if (lrow < nq) {
                    const long grow = (long)(gstart + qt * 64 + lrow);
                    q[grow * DIM + hh * DH + fs * 80 + f * 16 + l15] =
                        f2b(oacc[a][f][r] * invl[a][r]);
                }
            }
        }
    }
}

// ---------------- orchestration ------------------------------------------------
extern "C" void kernel_launch(void* const* d_in, const int* in_sizes, int n_in,
                              void* d_out, int out_size, void* d_ws, size_t ws_size,
                              hipStream_t stream) {
    const float* x     = (const float*)d_in[0];
    const int*   batch = (const int*)d_in[1];
    const float* Wqkv  = (const float*)d_in[2];
    const float* bqkv  = (const float*)d_in[3];
    const float* Wo    = (const float*)d_in[4];
    const float* bo    = (const float*)d_in[5];
    const float* ln1w  = (const float*)d_in[6];
    const float* ln1b  = (const float*)d_in[7];
    const float* W1    = (const float*)d_in[8];
    const float* b1    = (const float*)d_in[9];
    const float* W2    = (const float*)d_in[10];
    const float* b2    = (const float*)d_in[11];
    const float* ln2w  = (const float*)d_in[12];
    const float* ln2b  = (const float*)d_in[13];
    const float* Wm1   = (const float*)d_in[14];
    const float* bm1   = (const float*)d_in[15];
    const float* Wm2   = (const float*)d_in[16];
    const float* bm2   = (const float*)d_in[17];

    float* outF = (float*)d_out;
    u16*   qbuf = (u16*)d_out;   // first half doubles as bf16 q scratch

    char* ws   = (char*)d_ws;
    int*  offs = (int*)ws;
    u16*  h    = (u16*)(ws + 1024);
    u16*  kvb  = h + (size_t)N_TOK * DIM;
    u16*  tmp  = kvb;                           // alias, live only after attn
    u16*  ff   = kvb + (size_t)N_TOK * DIM;     // alias, disjoint from tmp
    u16*  wqkv_bf = kvb + (size_t)N_TOK * KVD;
    u16*  wo_bf   = wqkv_bf + (size_t)NLAYER * TD * DIM;
    u16*  w1_bf   = wo_bf   + (size_t)NLAYER * DIM * DIM;
    u16*  w2_bf   = w1_bf   + (size_t)NLAYER * FFD * DIM;
    u16*  wm1_bf  = w2_bf   + (size_t)NLAYER * DIM * FFD;
    u16*  wm2_bf  = wm1_bf  + (size_t)FFD * DIM;

    k_offsets<<<1, 128, 0, stream>>>(batch, offs);
    {
        long n = (long)N_TOK * DIM;
        k_f32_to_bf16<<<(int)(n / 1024), 256, 0, stream>>>(x, h, n);
        k_conv_weights<<<(int)(E5 / 1024), 256, 0, stream>>>(
            Wqkv, Wo, W1, W2, Wm1, Wm2,
            wqkv_bf, wo_bf, w1_bf, w2_bf, wm1_bf, wm2_bf);
    }

    dim3 blk(256);
    for (int l = 0; l < NLAYER; ++l) {
        const u16*   Wl = wqkv_bf + (size_t)l * TD * DIM;
        const float* bl = bqkv + (size_t)l * TD;
        // fused qkv: q -> qbuf, kv -> kvb
        k_gemm_qkv<<<dim3(TD / 128, N_TOK / 128), blk, 0, stream>>>(
            h, Wl, bl, qbuf, kvb);
        k_attn_mfma<<<dim3(10 * NH * NB), dim3(512), 0, stream>>>(qbuf, kvb, offs);
        k_gemm_mfma<<<dim3(DIM / 128, N_TOK / 128), blk, 0, stream>>>(
            qbuf, DIM, wo_bf + (size_t)l * DIM * DIM, bo + (size_t)l * DIM,
            tmp, DIM, DIM, 0, 0);
        k_ln_residual<<<N_TOK / 4, blk, 0, stream>>>(
            h, tmp, ln1w + (size_t)l * DIM, ln1b + (size_t)l * DIM, h);
        k_gemm_mfma<<<dim3(FFD / 128, N_TOK / 128), blk, 0, stream>>>(
            h, DIM, w1_bf + (size_t)l * FFD * DIM, b1 + (size_t)l * FFD,
            ff, FFD, DIM, 1, 0);
        k_gemm_mfma<<<dim3(DIM / 128, N_TOK / 128), blk, 0, stream>>>(
            ff, FFD, w2_bf + (size_t)l * DIM * FFD, b2 + (size_t)l * DIM,
            tmp, DIM, FFD, 0, 0);
        k_ln_residual<<<N_TOK / 4, blk, 0, stream>>>(
            h, tmp, ln2w + (size_t)l * DIM, ln2b + (size_t)l * DIM, h);
    }
    k_gemm_mfma<<<dim3(FFD / 128, N_TOK / 128), blk, 0, stream>>>(
        h, DIM, wm1_bf, bm1, ff, FFD, DIM, 1, 0);
    k_gemm_mfma<<<dim3(DIM / 128, N_TOK / 128), blk, 0, stream>>>(
        ff, FFD, wm2_bf, bm2, outF, DIM, FFD, 0, 1);
}